// Round 5
// baseline (148.243 us; speedup 1.0000x reference)
//
#include <hip/hip_runtime.h>
#include <hip/hip_fp16.h>

#define LEAKY_SLOPE 0.2f

__device__ __forceinline__ float leaky_relu_f(float v) { return v > 0.f ? v : LEAKY_SLOPE * v; }
__device__ __forceinline__ float selu_f(float v) {
    const float sc = 1.0507009873554805f, al = 1.6732632423543772f;
    return v > 0.f ? sc * v : sc * al * expm1f(v);
}

// Per-wave edge dtype detection: int64 => high words (odd int32 slots) all 0.
__device__ __forceinline__ int detect_is64_wave(const int* __restrict__ e32) {
    int v = e32[2 * (threadIdx.x & 63) + 1];
    unsigned long long b = __ballot(v != 0);
    return b == 0ull ? 1 : 0;
}

__device__ __forceinline__ int edge_at(const void* edges, long long idx, int is64) {
    return is64 ? (int)((const long long*)edges)[idx] : ((const int*)edges)[idx];
}

// ---------------------------------------------------------------------------
// GEMM + logits. 32 nodes/block, 256 threads, W staged in TWO 32KB K-halves
// (LDS 32KB -> ~5 blocks/CU residency vs 2 at 64KB). Thread (trow=t>>4,
// tcol=t&15): 2 nodes x 8 couts {c0..+3, 64+c0..+3}. Epilogue: fp16 x store +
// per-head logits via 4-lane shfl_xor reduce. Block 0 inits sentinel rows.
// ---------------------------------------------------------------------------
__global__ __launch_bounds__(256) void gemm_kernel(const float* __restrict__ feats,
                                                   const float* __restrict__ W,
                                                   const float* __restrict__ att_src,
                                                   const float* __restrict__ att_dst,
                                                   __half* __restrict__ xh,
                                                   float* __restrict__ a_src,
                                                   float* __restrict__ a_dst, int N) {
    __shared__ float Wlds[64 * 128];  // 32 KiB
    int t = threadIdx.x;

    if (blockIdx.x == 0) {  // sentinel rows for padded-CSR aggregation
        if (t < 64) *(__half2*)&xh[(long long)N * 128 + 2 * t] = __floats2half2_rn(0.f, 0.f);
        if (t < 8) a_src[N * 8 + t] = -1e30f;
    }

    const int tcol = t & 15;
    const int trow = t >> 4;
    const int c0 = tcol * 4;
    const int nbase = blockIdx.x * 32 + trow * 2;

    float acc[2][8];
#pragma unroll
    for (int i = 0; i < 2; i++)
#pragma unroll
        for (int j = 0; j < 8; j++) acc[i][j] = 0.f;

    int n[2];
#pragma unroll
    for (int i = 0; i < 2; i++) {
        int nn = nbase + i;
        n[i] = nn < N ? nn : N - 1;
    }

    for (int ks = 0; ks < 128; ks += 64) {
        // stage W rows [ks, ks+64) : 2048 float4, 8 per thread
        __syncthreads();
        {
            const float4* W4 = (const float4*)W;
            float4* Wl4 = (float4*)Wlds;
#pragma unroll
            for (int i = 0; i < 8; i++) Wl4[t + i * 256] = W4[ks * 32 + t + i * 256];
        }
        __syncthreads();

        for (int k = 0; k < 64; k += 4) {
            float4 f[2];
#pragma unroll
            for (int i = 0; i < 2; i++)
                f[i] = *(const float4*)&feats[(long long)n[i] * 128 + ks + k];
#pragma unroll
            for (int kk = 0; kk < 4; kk++) {
                float4 wA = *(const float4*)&Wlds[(k + kk) * 128 + c0];
                float4 wB = *(const float4*)&Wlds[(k + kk) * 128 + 64 + c0];
#pragma unroll
                for (int i = 0; i < 2; i++) {
                    float fv = (kk == 0) ? f[i].x : (kk == 1) ? f[i].y : (kk == 2) ? f[i].z : f[i].w;
                    acc[i][0] = fmaf(fv, wA.x, acc[i][0]);
                    acc[i][1] = fmaf(fv, wA.y, acc[i][1]);
                    acc[i][2] = fmaf(fv, wA.z, acc[i][2]);
                    acc[i][3] = fmaf(fv, wA.w, acc[i][3]);
                    acc[i][4] = fmaf(fv, wB.x, acc[i][4]);
                    acc[i][5] = fmaf(fv, wB.y, acc[i][5]);
                    acc[i][6] = fmaf(fv, wB.z, acc[i][6]);
                    acc[i][7] = fmaf(fv, wB.w, acc[i][7]);
                }
            }
        }
    }

    const int h0 = tcol >> 2;
    const int h1 = h0 + 4;
    const int co = (tcol & 3) * 4;
    float4 as0 = *(const float4*)&att_src[h0 * 16 + co];
    float4 as1 = *(const float4*)&att_src[h1 * 16 + co];
    float4 ad0 = *(const float4*)&att_dst[h0 * 16 + co];
    float4 ad1 = *(const float4*)&att_dst[h1 * 16 + co];

#pragma unroll
    for (int i = 0; i < 2; i++) {
        int nn = nbase + i;
        if (nn < N) {
            union { __half2 h2[2]; uint2 u; } uA, uB;
            uA.h2[0] = __floats2half2_rn(acc[i][0], acc[i][1]);
            uA.h2[1] = __floats2half2_rn(acc[i][2], acc[i][3]);
            uB.h2[0] = __floats2half2_rn(acc[i][4], acc[i][5]);
            uB.h2[1] = __floats2half2_rn(acc[i][6], acc[i][7]);
            *(uint2*)&xh[(long long)nn * 128 + c0] = uA.u;
            *(uint2*)&xh[(long long)nn * 128 + 64 + c0] = uB.u;
        }
        float psA = acc[i][0] * as0.x + acc[i][1] * as0.y + acc[i][2] * as0.z + acc[i][3] * as0.w;
        float pdA = acc[i][0] * ad0.x + acc[i][1] * ad0.y + acc[i][2] * ad0.z + acc[i][3] * ad0.w;
        float psB = acc[i][4] * as1.x + acc[i][5] * as1.y + acc[i][6] * as1.z + acc[i][7] * as1.w;
        float pdB = acc[i][4] * ad1.x + acc[i][5] * ad1.y + acc[i][6] * ad1.z + acc[i][7] * ad1.w;
        psA += __shfl_xor(psA, 1); psA += __shfl_xor(psA, 2);
        pdA += __shfl_xor(pdA, 1); pdA += __shfl_xor(pdA, 2);
        psB += __shfl_xor(psB, 1); psB += __shfl_xor(psB, 2);
        pdB += __shfl_xor(pdB, 1); pdB += __shfl_xor(pdB, 2);
        if ((t & 1) == i && (t & 2) == 0 && nn < N) {
            a_src[nn * 8 + h0] = psA;
            a_src[nn * 8 + h1] = psB;
            a_dst[nn * 8 + h0] = pdA;
            a_dst[nn * 8 + h1] = pdB;
        }
    }
}

// ---------------------------------------------------------------------------
// CSR build: histogram -> padded two-level scan -> pad-fill -> scatter.
// ---------------------------------------------------------------------------
__global__ void hist_kernel(const void* __restrict__ edges, long long E,
                            int* __restrict__ deg) {
    int is64 = detect_is64_wave((const int*)edges);
    long long stride = (long long)gridDim.x * blockDim.x;
    for (long long e = (long long)blockIdx.x * blockDim.x + threadIdx.x; e < E; e += stride) {
        int dst = edge_at(edges, E + e, is64);
        atomicAdd(&deg[dst], 1);
    }
}

__global__ __launch_bounds__(256) void scan1_kernel(const int* __restrict__ deg,
                                                    int* __restrict__ offs,
                                                    int* __restrict__ bsum, int N) {
    __shared__ int lds[256];
    int t = threadIdx.x;
    int base = blockIdx.x * 1024 + t * 4;
    int v[4];
    int s = 0;
#pragma unroll
    for (int i = 0; i < 4; i++) {
        v[i] = (base + i < N) ? ((deg[base + i] + 7) & ~7) : 0;
        s += v[i];
    }
    lds[t] = s;
    __syncthreads();
    for (int off = 1; off < 256; off <<= 1) {
        int u = (t >= off) ? lds[t - off] : 0;
        __syncthreads();
        lds[t] += u;
        __syncthreads();
    }
    if (t == 255) bsum[blockIdx.x] = lds[255];
    int run = (t == 0) ? 0 : lds[t - 1];
#pragma unroll
    for (int i = 0; i < 4; i++) {
        if (base + i < N) offs[base + i] = run;
        run += v[i];
    }
}

__global__ __launch_bounds__(1024) void scan2_kernel(int* __restrict__ bsum, int nb) {
    __shared__ int lds[1024];
    int t = threadIdx.x;
    int v = (t < nb) ? bsum[t] : 0;
    lds[t] = v;
    __syncthreads();
    for (int off = 1; off < 1024; off <<= 1) {
        int u = (t >= off) ? lds[t - off] : 0;
        __syncthreads();
        lds[t] += u;
        __syncthreads();
    }
    if (t < nb) bsum[t] = lds[t] - v;  // exclusive
    if (t == nb - 1) bsum[nb] = lds[t];  // grand total (padded E)
}

// scan3: globalize offsets, fill cursor, write sentinel N into the <=7 pad
// slots of each node's segment, set offs[N].
__global__ void scan3_kernel(int* __restrict__ offs, int* __restrict__ cursor,
                             const int* __restrict__ bsum, const int* __restrict__ deg,
                             int* __restrict__ csr, int N, int nb) {
    int idx = blockIdx.x * blockDim.x + threadIdx.x;
    if (idx < N) {
        int o = offs[idx] + bsum[idx >> 10];
        offs[idx] = o;
        cursor[idx] = o;
        int d = deg[idx];
        int pd = (d + 7) & ~7;
        for (int q = o + d; q < o + pd; q++) csr[q] = N;
    }
    if (idx == N) offs[N] = bsum[nb];
}

__global__ void scatter_kernel(const void* __restrict__ edges, long long E,
                               int* __restrict__ cursor, int* __restrict__ csr) {
    int is64 = detect_is64_wave((const int*)edges);
    long long stride = (long long)gridDim.x * blockDim.x;
    for (long long e = (long long)blockIdx.x * blockDim.x + threadIdx.x; e < E; e += stride) {
        int src = edge_at(edges, e, is64);
        int dst = edge_at(edges, E + e, is64);
        int pos = atomicAdd(&cursor[dst], 1);
        csr[pos] = src;
    }
}

// ---------------------------------------------------------------------------
// Aggregate: one wave per node, single pass, padded straight-line 8-wide
// gathers, next-batch csr/a_src prefetch. (unchanged from R4)
// ---------------------------------------------------------------------------
__global__ __launch_bounds__(256) void agg_kernel(const __half* __restrict__ xh,
                                                  const float* __restrict__ a_src,
                                                  const float* __restrict__ a_dst,
                                                  const int* __restrict__ offs,
                                                  const int* __restrict__ csr,
                                                  const float* __restrict__ bias,
                                                  float* __restrict__ out, int N) {
    int node = blockIdx.x * 4 + (threadIdx.x >> 6);
    if (node >= N) return;
    int l = threadIdx.x & 63;
    int h8 = l & 7;
    int e8 = l >> 3;
    int hg = l >> 3;

    float ad_w = a_dst[node * 8 + h8];
    float wself = expf(leaky_relu_f(a_src[node * 8 + h8] + ad_w));
    float spart = (e8 == 0) ? wself : 0.f;

    float wself_h = __shfl(wself, hg);
    float2 xs = __half22float2(*(const __half2*)&xh[(long long)node * 128 + 2 * l]);
    float accx = wself_h * xs.x;
    float accy = wself_h * xs.y;

    int beg = offs[node], end = offs[node + 1];
    int srcv = 0;
    float w = 0.f;
    if (beg < end) {
        srcv = csr[beg + e8];
        w = expf(leaky_relu_f(a_src[srcv * 8 + h8] + ad_w));
    }
    for (int p = beg; p < end; p += 8) {
        spart += w;
        int pn = p + 8;
        int srcv_n = 0;
        float asv_n = 0.f;
        bool more = pn < end;
        if (more) {
            srcv_n = csr[pn + e8];
            asv_n = a_src[srcv_n * 8 + h8];
        }
        float wcur = w;
        int srcv_c = srcv;
#pragma unroll
        for (int e = 0; e < 8; e++) {
            int src = __shfl(srcv_c, e * 8);
            float we = __shfl(wcur, e * 8 + hg);
            float2 xv = __half22float2(*(const __half2*)&xh[(long long)src * 128 + 2 * l]);
            accx = fmaf(we, xv.x, accx);
            accy = fmaf(we, xv.y, accy);
        }
        w = more ? expf(leaky_relu_f(asv_n + ad_w)) : 0.f;
        srcv = srcv_n;
    }
    spart += __shfl_xor(spart, 8);
    spart += __shfl_xor(spart, 16);
    spart += __shfl_xor(spart, 32);
    float s = __shfl(spart, hg);
    float inv = 1.f / (s + 1e-16f);

    float2 b = *(const float2*)&bias[2 * l];
    float2 o;
    o.x = selu_f(fmaf(accx, inv, b.x));
    o.y = selu_f(fmaf(accy, inv, b.y));
    *(float2*)&out[(long long)node * 128 + 2 * l] = o;
}

extern "C" void kernel_launch(void* const* d_in, const int* in_sizes, int n_in,
                              void* d_out, int out_size, void* d_ws, size_t ws_size,
                              hipStream_t stream) {
    const float* feats   = (const float*)d_in[0];
    const void*  edges   = d_in[1];
    const float* W       = (const float*)d_in[2];
    const float* att_src = (const float*)d_in[3];
    const float* att_dst = (const float*)d_in[4];
    const float* bias    = (const float*)d_in[5];

    const int N = in_sizes[0] / 128;
    const long long E = in_sizes[1] / 2;
    const long long fillE = E + 7LL * N;
    float* out = (float*)d_out;

    char* ws = (char*)d_ws;
    __half* xh    = (__half*)ws; ws += (size_t)(N + 1) * 128 * 2;
    float* a_src  = (float*)ws;  ws += (size_t)(N + 1) * 8 * 4;
    float* a_dst  = (float*)ws;  ws += (size_t)N * 8 * 4;
    int*   deg    = (int*)ws;    ws += (size_t)N * 4;
    int*   offs   = (int*)ws;    ws += (size_t)(N + 1) * 4;
    int*   cursor = (int*)ws;    ws += (size_t)N * 4;
    int*   bsum   = (int*)ws;    ws += 1028 * 4;
    int*   csr    = (int*)ws;    ws += (size_t)fillE * 4;

    hipMemsetAsync(deg, 0, (size_t)N * 4, stream);

    int nb = (N + 1023) / 1024;
    hist_kernel<<<2048, 256, 0, stream>>>(edges, E, deg);
    scan1_kernel<<<nb, 256, 0, stream>>>(deg, offs, bsum, N);
    scan2_kernel<<<1, 1024, 0, stream>>>(bsum, nb);
    scan3_kernel<<<(N + 256) / 256, 256, 0, stream>>>(offs, cursor, bsum, deg, csr, N, nb);
    gemm_kernel<<<(N + 31) / 32, 256, 0, stream>>>(feats, W, att_src, att_dst, xh, a_src, a_dst, N);
    scatter_kernel<<<2048, 256, 0, stream>>>(edges, E, cursor, csr);
    agg_kernel<<<(N + 3) / 4, 256, 0, stream>>>(xh, a_src, a_dst, offs, csr, bias, out, N);
}

// Round 6
// 144.754 us; speedup vs baseline: 1.0241x; 1.0241x over previous
//
#include <hip/hip_runtime.h>
#include <hip/hip_fp16.h>

#define LEAKY_SLOPE 0.2f

__device__ __forceinline__ float leaky_relu_f(float v) { return v > 0.f ? v : LEAKY_SLOPE * v; }
__device__ __forceinline__ float selu_f(float v) {
    const float sc = 1.0507009873554805f, al = 1.6732632423543772f;
    return v > 0.f ? sc * v : sc * al * expm1f(v);
}

// Per-wave edge dtype detection: int64 => high words (odd int32 slots) all 0.
__device__ __forceinline__ int detect_is64_wave(const int* __restrict__ e32) {
    int v = e32[2 * (threadIdx.x & 63) + 1];
    unsigned long long b = __ballot(v != 0);
    return b == 0ull ? 1 : 0;
}

__device__ __forceinline__ int edge_at(const void* edges, long long idx, int is64) {
    return is64 ? (int)((const long long*)edges)[idx] : ((const int*)edges)[idx];
}

// Zero deg[] ourselves: the rocclr fillBuffer kernel takes 43us for 200KB
// (latency-bound tiny-grid fill); this takes ~3us.
__global__ void zero_kernel(int* __restrict__ p, int n) {
    int i = blockIdx.x * blockDim.x + threadIdx.x;
    if (i < n) p[i] = 0;
}

// ---------------------------------------------------------------------------
// GEMM + logits. 32 nodes/block, 256 threads, W staged in TWO 32KB K-halves.
// Thread (trow=t>>4, tcol=t&15): 2 nodes x 8 couts. Epilogue: fp16 x store +
// per-head logits via 4-lane shfl_xor reduce. Block 0 inits sentinel rows.
// ---------------------------------------------------------------------------
__global__ __launch_bounds__(256) void gemm_kernel(const float* __restrict__ feats,
                                                   const float* __restrict__ W,
                                                   const float* __restrict__ att_src,
                                                   const float* __restrict__ att_dst,
                                                   __half* __restrict__ xh,
                                                   float* __restrict__ a_src,
                                                   float* __restrict__ a_dst, int N) {
    __shared__ float Wlds[64 * 128];  // 32 KiB
    int t = threadIdx.x;

    if (blockIdx.x == 0) {  // sentinel rows for padded-CSR aggregation
        if (t < 64) *(__half2*)&xh[(long long)N * 128 + 2 * t] = __floats2half2_rn(0.f, 0.f);
        if (t < 8) a_src[N * 8 + t] = -1e30f;
    }

    const int tcol = t & 15;
    const int trow = t >> 4;
    const int c0 = tcol * 4;
    const int nbase = blockIdx.x * 32 + trow * 2;

    float acc[2][8];
#pragma unroll
    for (int i = 0; i < 2; i++)
#pragma unroll
        for (int j = 0; j < 8; j++) acc[i][j] = 0.f;

    int n[2];
#pragma unroll
    for (int i = 0; i < 2; i++) {
        int nn = nbase + i;
        n[i] = nn < N ? nn : N - 1;
    }

    for (int ks = 0; ks < 128; ks += 64) {
        __syncthreads();
        {
            const float4* W4 = (const float4*)W;
            float4* Wl4 = (float4*)Wlds;
#pragma unroll
            for (int i = 0; i < 8; i++) Wl4[t + i * 256] = W4[ks * 32 + t + i * 256];
        }
        __syncthreads();

        for (int k = 0; k < 64; k += 4) {
            float4 f[2];
#pragma unroll
            for (int i = 0; i < 2; i++)
                f[i] = *(const float4*)&feats[(long long)n[i] * 128 + ks + k];
#pragma unroll
            for (int kk = 0; kk < 4; kk++) {
                float4 wA = *(const float4*)&Wlds[(k + kk) * 128 + c0];
                float4 wB = *(const float4*)&Wlds[(k + kk) * 128 + 64 + c0];
#pragma unroll
                for (int i = 0; i < 2; i++) {
                    float fv = (kk == 0) ? f[i].x : (kk == 1) ? f[i].y : (kk == 2) ? f[i].z : f[i].w;
                    acc[i][0] = fmaf(fv, wA.x, acc[i][0]);
                    acc[i][1] = fmaf(fv, wA.y, acc[i][1]);
                    acc[i][2] = fmaf(fv, wA.z, acc[i][2]);
                    acc[i][3] = fmaf(fv, wA.w, acc[i][3]);
                    acc[i][4] = fmaf(fv, wB.x, acc[i][4]);
                    acc[i][5] = fmaf(fv, wB.y, acc[i][5]);
                    acc[i][6] = fmaf(fv, wB.z, acc[i][6]);
                    acc[i][7] = fmaf(fv, wB.w, acc[i][7]);
                }
            }
        }
    }

    const int h0 = tcol >> 2;
    const int h1 = h0 + 4;
    const int co = (tcol & 3) * 4;
    float4 as0 = *(const float4*)&att_src[h0 * 16 + co];
    float4 as1 = *(const float4*)&att_src[h1 * 16 + co];
    float4 ad0 = *(const float4*)&att_dst[h0 * 16 + co];
    float4 ad1 = *(const float4*)&att_dst[h1 * 16 + co];

#pragma unroll
    for (int i = 0; i < 2; i++) {
        int nn = nbase + i;
        if (nn < N) {
            union { __half2 h2[2]; uint2 u; } uA, uB;
            uA.h2[0] = __floats2half2_rn(acc[i][0], acc[i][1]);
            uA.h2[1] = __floats2half2_rn(acc[i][2], acc[i][3]);
            uB.h2[0] = __floats2half2_rn(acc[i][4], acc[i][5]);
            uB.h2[1] = __floats2half2_rn(acc[i][6], acc[i][7]);
            *(uint2*)&xh[(long long)nn * 128 + c0] = uA.u;
            *(uint2*)&xh[(long long)nn * 128 + 64 + c0] = uB.u;
        }
        float psA = acc[i][0] * as0.x + acc[i][1] * as0.y + acc[i][2] * as0.z + acc[i][3] * as0.w;
        float pdA = acc[i][0] * ad0.x + acc[i][1] * ad0.y + acc[i][2] * ad0.z + acc[i][3] * ad0.w;
        float psB = acc[i][4] * as1.x + acc[i][5] * as1.y + acc[i][6] * as1.z + acc[i][7] * as1.w;
        float pdB = acc[i][4] * ad1.x + acc[i][5] * ad1.y + acc[i][6] * ad1.z + acc[i][7] * ad1.w;
        psA += __shfl_xor(psA, 1); psA += __shfl_xor(psA, 2);
        pdA += __shfl_xor(pdA, 1); pdA += __shfl_xor(pdA, 2);
        psB += __shfl_xor(psB, 1); psB += __shfl_xor(psB, 2);
        pdB += __shfl_xor(pdB, 1); pdB += __shfl_xor(pdB, 2);
        if ((t & 1) == i && (t & 2) == 0 && nn < N) {
            a_src[nn * 8 + h0] = psA;
            a_src[nn * 8 + h1] = psB;
            a_dst[nn * 8 + h0] = pdA;
            a_dst[nn * 8 + h1] = pdB;
        }
    }
}

// ---------------------------------------------------------------------------
// CSR build: histogram -> padded two-level scan -> pad-fill -> scatter.
// ---------------------------------------------------------------------------
__global__ void hist_kernel(const void* __restrict__ edges, long long E,
                            int* __restrict__ deg) {
    int is64 = detect_is64_wave((const int*)edges);
    long long stride = (long long)gridDim.x * blockDim.x;
    for (long long e = (long long)blockIdx.x * blockDim.x + threadIdx.x; e < E; e += stride) {
        int dst = edge_at(edges, E + e, is64);
        atomicAdd(&deg[dst], 1);
    }
}

__global__ __launch_bounds__(256) void scan1_kernel(const int* __restrict__ deg,
                                                    int* __restrict__ offs,
                                                    int* __restrict__ bsum, int N) {
    __shared__ int lds[256];
    int t = threadIdx.x;
    int base = blockIdx.x * 1024 + t * 4;
    int v[4];
    int s = 0;
#pragma unroll
    for (int i = 0; i < 4; i++) {
        v[i] = (base + i < N) ? ((deg[base + i] + 7) & ~7) : 0;
        s += v[i];
    }
    lds[t] = s;
    __syncthreads();
    for (int off = 1; off < 256; off <<= 1) {
        int u = (t >= off) ? lds[t - off] : 0;
        __syncthreads();
        lds[t] += u;
        __syncthreads();
    }
    if (t == 255) bsum[blockIdx.x] = lds[255];
    int run = (t == 0) ? 0 : lds[t - 1];
#pragma unroll
    for (int i = 0; i < 4; i++) {
        if (base + i < N) offs[base + i] = run;
        run += v[i];
    }
}

__global__ __launch_bounds__(1024) void scan2_kernel(int* __restrict__ bsum, int nb) {
    __shared__ int lds[1024];
    int t = threadIdx.x;
    int v = (t < nb) ? bsum[t] : 0;
    lds[t] = v;
    __syncthreads();
    for (int off = 1; off < 1024; off <<= 1) {
        int u = (t >= off) ? lds[t - off] : 0;
        __syncthreads();
        lds[t] += u;
        __syncthreads();
    }
    if (t < nb) bsum[t] = lds[t] - v;  // exclusive
    if (t == nb - 1) bsum[nb] = lds[t];  // grand total (padded E)
}

__global__ void scan3_kernel(int* __restrict__ offs, int* __restrict__ cursor,
                             const int* __restrict__ bsum, const int* __restrict__ deg,
                             int* __restrict__ csr, int N, int nb) {
    int idx = blockIdx.x * blockDim.x + threadIdx.x;
    if (idx < N) {
        int o = offs[idx] + bsum[idx >> 10];
        offs[idx] = o;
        cursor[idx] = o;
        int d = deg[idx];
        int pd = (d + 7) & ~7;
        for (int q = o + d; q < o + pd; q++) csr[q] = N;
    }
    if (idx == N) offs[N] = bsum[nb];
}

__global__ void scatter_kernel(const void* __restrict__ edges, long long E,
                               int* __restrict__ cursor, int* __restrict__ csr) {
    int is64 = detect_is64_wave((const int*)edges);
    long long stride = (long long)gridDim.x * blockDim.x;
    for (long long e = (long long)blockIdx.x * blockDim.x + threadIdx.x; e < E; e += stride) {
        int src = edge_at(edges, e, is64);
        int dst = edge_at(edges, E + e, is64);
        int pos = atomicAdd(&cursor[dst], 1);
        csr[pos] = src;
    }
}

// ---------------------------------------------------------------------------
// Aggregate: one wave per node, single pass, padded straight-line 8-wide
// gathers, next-batch csr/a_src prefetch.
// ---------------------------------------------------------------------------
__global__ __launch_bounds__(256) void agg_kernel(const __half* __restrict__ xh,
                                                  const float* __restrict__ a_src,
                                                  const float* __restrict__ a_dst,
                                                  const int* __restrict__ offs,
                                                  const int* __restrict__ csr,
                                                  const float* __restrict__ bias,
                                                  float* __restrict__ out, int N) {
    int node = blockIdx.x * 4 + (threadIdx.x >> 6);
    if (node >= N) return;
    int l = threadIdx.x & 63;
    int h8 = l & 7;
    int e8 = l >> 3;
    int hg = l >> 3;

    float ad_w = a_dst[node * 8 + h8];
    float wself = expf(leaky_relu_f(a_src[node * 8 + h8] + ad_w));
    float spart = (e8 == 0) ? wself : 0.f;

    float wself_h = __shfl(wself, hg);
    float2 xs = __half22float2(*(const __half2*)&xh[(long long)node * 128 + 2 * l]);
    float accx = wself_h * xs.x;
    float accy = wself_h * xs.y;

    int beg = offs[node], end = offs[node + 1];
    int srcv = 0;
    float w = 0.f;
    if (beg < end) {
        srcv = csr[beg + e8];
        w = expf(leaky_relu_f(a_src[srcv * 8 + h8] + ad_w));
    }
    for (int p = beg; p < end; p += 8) {
        spart += w;
        int pn = p + 8;
        int srcv_n = 0;
        float asv_n = 0.f;
        bool more = pn < end;
        if (more) {
            srcv_n = csr[pn + e8];
            asv_n = a_src[srcv_n * 8 + h8];
        }
        float wcur = w;
        int srcv_c = srcv;
#pragma unroll
        for (int e = 0; e < 8; e++) {
            int src = __shfl(srcv_c, e * 8);
            float we = __shfl(wcur, e * 8 + hg);
            float2 xv = __half22float2(*(const __half2*)&xh[(long long)src * 128 + 2 * l]);
            accx = fmaf(we, xv.x, accx);
            accy = fmaf(we, xv.y, accy);
        }
        w = more ? expf(leaky_relu_f(asv_n + ad_w)) : 0.f;
        srcv = srcv_n;
    }
    spart += __shfl_xor(spart, 8);
    spart += __shfl_xor(spart, 16);
    spart += __shfl_xor(spart, 32);
    float s = __shfl(spart, hg);
    float inv = 1.f / (s + 1e-16f);

    float2 b = *(const float2*)&bias[2 * l];
    float2 o;
    o.x = selu_f(fmaf(accx, inv, b.x));
    o.y = selu_f(fmaf(accy, inv, b.y));
    *(float2*)&out[(long long)node * 128 + 2 * l] = o;
}

extern "C" void kernel_launch(void* const* d_in, const int* in_sizes, int n_in,
                              void* d_out, int out_size, void* d_ws, size_t ws_size,
                              hipStream_t stream) {
    const float* feats   = (const float*)d_in[0];
    const void*  edges   = d_in[1];
    const float* W       = (const float*)d_in[2];
    const float* att_src = (const float*)d_in[3];
    const float* att_dst = (const float*)d_in[4];
    const float* bias    = (const float*)d_in[5];

    const int N = in_sizes[0] / 128;
    const long long E = in_sizes[1] / 2;
    const long long fillE = E + 7LL * N;
    float* out = (float*)d_out;

    char* ws = (char*)d_ws;
    __half* xh    = (__half*)ws; ws += (size_t)(N + 1) * 128 * 2;
    float* a_src  = (float*)ws;  ws += (size_t)(N + 1) * 8 * 4;
    float* a_dst  = (float*)ws;  ws += (size_t)N * 8 * 4;
    int*   deg    = (int*)ws;    ws += (size_t)N * 4;
    int*   offs   = (int*)ws;    ws += (size_t)(N + 1) * 4;
    int*   cursor = (int*)ws;    ws += (size_t)N * 4;
    int*   bsum   = (int*)ws;    ws += 1028 * 4;
    int*   csr    = (int*)ws;    ws += (size_t)fillE * 4;

    int nb = (N + 1023) / 1024;
    zero_kernel<<<(N + 255) / 256, 256, 0, stream>>>(deg, N);
    hist_kernel<<<2048, 256, 0, stream>>>(edges, E, deg);
    scan1_kernel<<<nb, 256, 0, stream>>>(deg, offs, bsum, N);
    scan2_kernel<<<1, 1024, 0, stream>>>(bsum, nb);
    scan3_kernel<<<(N + 256) / 256, 256, 0, stream>>>(offs, cursor, bsum, deg, csr, N, nb);
    gemm_kernel<<<(N + 31) / 32, 256, 0, stream>>>(feats, W, att_src, att_dst, xh, a_src, a_dst, N);
    scatter_kernel<<<2048, 256, 0, stream>>>(edges, E, cursor, csr);
    agg_kernel<<<(N + 3) / 4, 256, 0, stream>>>(xh, a_src, a_dst, offs, csr, bias, out, N);
}

// Round 7
// 123.463 us; speedup vs baseline: 1.2007x; 1.1724x over previous
//
#include <hip/hip_runtime.h>
#include <hip/hip_fp16.h>

#define LEAKY_SLOPE 0.2f

__device__ __forceinline__ float leaky_relu_f(float v) { return v > 0.f ? v : LEAKY_SLOPE * v; }
__device__ __forceinline__ float selu_f(float v) {
    const float sc = 1.0507009873554805f, al = 1.6732632423543772f;
    return v > 0.f ? sc * v : sc * al * expm1f(v);
}

// Per-wave edge dtype detection: int64 => high words (odd int32 slots) all 0.
__device__ __forceinline__ int detect_is64_wave(const int* __restrict__ e32) {
    int v = e32[2 * (threadIdx.x & 63) + 1];
    unsigned long long b = __ballot(v != 0);
    return b == 0ull ? 1 : 0;
}

__device__ __forceinline__ int edge_at(const void* edges, long long idx, int is64) {
    return is64 ? (int)((const long long*)edges)[idx] : ((const int*)edges)[idx];
}

// Zero deg[]: rocclr fillBuffer takes 43us for 200KB; this takes ~3us.
__global__ void zero_kernel(int* __restrict__ p, int n) {
    int i = blockIdx.x * blockDim.x + threadIdx.x;
    if (i < n) p[i] = 0;
}

// ---------------------------------------------------------------------------
// GEMM + logits. 32 nodes/block, 256 threads, W staged in TWO 32KB K-halves.
// ---------------------------------------------------------------------------
__global__ __launch_bounds__(256) void gemm_kernel(const float* __restrict__ feats,
                                                   const float* __restrict__ W,
                                                   const float* __restrict__ att_src,
                                                   const float* __restrict__ att_dst,
                                                   __half* __restrict__ xh,
                                                   float* __restrict__ a_src,
                                                   float* __restrict__ a_dst, int N) {
    __shared__ float Wlds[64 * 128];  // 32 KiB
    int t = threadIdx.x;

    if (blockIdx.x == 0) {  // sentinel rows for padded-CSR aggregation
        if (t < 64) *(__half2*)&xh[(long long)N * 128 + 2 * t] = __floats2half2_rn(0.f, 0.f);
        if (t < 8) a_src[N * 8 + t] = -1e30f;
    }

    const int tcol = t & 15;
    const int trow = t >> 4;
    const int c0 = tcol * 4;
    const int nbase = blockIdx.x * 32 + trow * 2;

    float acc[2][8];
#pragma unroll
    for (int i = 0; i < 2; i++)
#pragma unroll
        for (int j = 0; j < 8; j++) acc[i][j] = 0.f;

    int n[2];
#pragma unroll
    for (int i = 0; i < 2; i++) {
        int nn = nbase + i;
        n[i] = nn < N ? nn : N - 1;
    }

    for (int ks = 0; ks < 128; ks += 64) {
        __syncthreads();
        {
            const float4* W4 = (const float4*)W;
            float4* Wl4 = (float4*)Wlds;
#pragma unroll
            for (int i = 0; i < 8; i++) Wl4[t + i * 256] = W4[ks * 32 + t + i * 256];
        }
        __syncthreads();

        for (int k = 0; k < 64; k += 4) {
            float4 f[2];
#pragma unroll
            for (int i = 0; i < 2; i++)
                f[i] = *(const float4*)&feats[(long long)n[i] * 128 + ks + k];
#pragma unroll
            for (int kk = 0; kk < 4; kk++) {
                float4 wA = *(const float4*)&Wlds[(k + kk) * 128 + c0];
                float4 wB = *(const float4*)&Wlds[(k + kk) * 128 + 64 + c0];
#pragma unroll
                for (int i = 0; i < 2; i++) {
                    float fv = (kk == 0) ? f[i].x : (kk == 1) ? f[i].y : (kk == 2) ? f[i].z : f[i].w;
                    acc[i][0] = fmaf(fv, wA.x, acc[i][0]);
                    acc[i][1] = fmaf(fv, wA.y, acc[i][1]);
                    acc[i][2] = fmaf(fv, wA.z, acc[i][2]);
                    acc[i][3] = fmaf(fv, wA.w, acc[i][3]);
                    acc[i][4] = fmaf(fv, wB.x, acc[i][4]);
                    acc[i][5] = fmaf(fv, wB.y, acc[i][5]);
                    acc[i][6] = fmaf(fv, wB.z, acc[i][6]);
                    acc[i][7] = fmaf(fv, wB.w, acc[i][7]);
                }
            }
        }
    }

    const int h0 = tcol >> 2;
    const int h1 = h0 + 4;
    const int co = (tcol & 3) * 4;
    float4 as0 = *(const float4*)&att_src[h0 * 16 + co];
    float4 as1 = *(const float4*)&att_src[h1 * 16 + co];
    float4 ad0 = *(const float4*)&att_dst[h0 * 16 + co];
    float4 ad1 = *(const float4*)&att_dst[h1 * 16 + co];

#pragma unroll
    for (int i = 0; i < 2; i++) {
        int nn = nbase + i;
        if (nn < N) {
            union { __half2 h2[2]; uint2 u; } uA, uB;
            uA.h2[0] = __floats2half2_rn(acc[i][0], acc[i][1]);
            uA.h2[1] = __floats2half2_rn(acc[i][2], acc[i][3]);
            uB.h2[0] = __floats2half2_rn(acc[i][4], acc[i][5]);
            uB.h2[1] = __floats2half2_rn(acc[i][6], acc[i][7]);
            *(uint2*)&xh[(long long)nn * 128 + c0] = uA.u;
            *(uint2*)&xh[(long long)nn * 128 + 64 + c0] = uB.u;
        }
        float psA = acc[i][0] * as0.x + acc[i][1] * as0.y + acc[i][2] * as0.z + acc[i][3] * as0.w;
        float pdA = acc[i][0] * ad0.x + acc[i][1] * ad0.y + acc[i][2] * ad0.z + acc[i][3] * ad0.w;
        float psB = acc[i][4] * as1.x + acc[i][5] * as1.y + acc[i][6] * as1.z + acc[i][7] * as1.w;
        float pdB = acc[i][4] * ad1.x + acc[i][5] * ad1.y + acc[i][6] * ad1.z + acc[i][7] * ad1.w;
        psA += __shfl_xor(psA, 1); psA += __shfl_xor(psA, 2);
        pdA += __shfl_xor(pdA, 1); pdA += __shfl_xor(pdA, 2);
        psB += __shfl_xor(psB, 1); psB += __shfl_xor(psB, 2);
        pdB += __shfl_xor(pdB, 1); pdB += __shfl_xor(pdB, 2);
        if ((t & 1) == i && (t & 2) == 0 && nn < N) {
            a_src[nn * 8 + h0] = psA;
            a_src[nn * 8 + h1] = psB;
            a_dst[nn * 8 + h0] = pdA;
            a_dst[nn * 8 + h1] = pdB;
        }
    }
}

// ---------------------------------------------------------------------------
// CSR build: histogram WITH RANK CAPTURE -> padded two-level scan -> pad-fill
// -> atomic-free scatter. The atomicAdd return value (free) is each edge's
// rank within its dst bucket, so scatter needs no cursor round-trip.
// ---------------------------------------------------------------------------
__global__ void hist_kernel(const void* __restrict__ edges, long long E,
                            int* __restrict__ deg, int* __restrict__ rank) {
    int is64 = detect_is64_wave((const int*)edges);
    long long stride = (long long)gridDim.x * blockDim.x;
    for (long long e = (long long)blockIdx.x * blockDim.x + threadIdx.x; e < E; e += stride) {
        int dst = edge_at(edges, E + e, is64);
        rank[e] = atomicAdd(&deg[dst], 1);
    }
}

__global__ __launch_bounds__(256) void scan1_kernel(const int* __restrict__ deg,
                                                    int* __restrict__ offs,
                                                    int* __restrict__ bsum, int N) {
    __shared__ int lds[256];
    int t = threadIdx.x;
    int base = blockIdx.x * 1024 + t * 4;
    int v[4];
    int s = 0;
#pragma unroll
    for (int i = 0; i < 4; i++) {
        v[i] = (base + i < N) ? ((deg[base + i] + 7) & ~7) : 0;
        s += v[i];
    }
    lds[t] = s;
    __syncthreads();
    for (int off = 1; off < 256; off <<= 1) {
        int u = (t >= off) ? lds[t - off] : 0;
        __syncthreads();
        lds[t] += u;
        __syncthreads();
    }
    if (t == 255) bsum[blockIdx.x] = lds[255];
    int run = (t == 0) ? 0 : lds[t - 1];
#pragma unroll
    for (int i = 0; i < 4; i++) {
        if (base + i < N) offs[base + i] = run;
        run += v[i];
    }
}

__global__ __launch_bounds__(1024) void scan2_kernel(int* __restrict__ bsum, int nb) {
    __shared__ int lds[1024];
    int t = threadIdx.x;
    int v = (t < nb) ? bsum[t] : 0;
    lds[t] = v;
    __syncthreads();
    for (int off = 1; off < 1024; off <<= 1) {
        int u = (t >= off) ? lds[t - off] : 0;
        __syncthreads();
        lds[t] += u;
        __syncthreads();
    }
    if (t < nb) bsum[t] = lds[t] - v;  // exclusive
    if (t == nb - 1) bsum[nb] = lds[t];  // grand total (padded E)
}

__global__ void scan3_kernel(int* __restrict__ offs, const int* __restrict__ bsum,
                             const int* __restrict__ deg, int* __restrict__ csr,
                             int N, int nb) {
    int idx = blockIdx.x * blockDim.x + threadIdx.x;
    if (idx < N) {
        int o = offs[idx] + bsum[idx >> 10];
        offs[idx] = o;
        int d = deg[idx];
        int pd = (d + 7) & ~7;
        for (int q = o + d; q < o + pd; q++) csr[q] = N;
    }
    if (idx == N) offs[N] = bsum[nb];
}

// Atomic-free scatter: csr[offs[dst] + rank[e]] = src.
__global__ void scatter_kernel(const void* __restrict__ edges, long long E,
                               const int* __restrict__ offs, const int* __restrict__ rank,
                               int* __restrict__ csr) {
    int is64 = detect_is64_wave((const int*)edges);
    long long stride = (long long)gridDim.x * blockDim.x;
    for (long long e = (long long)blockIdx.x * blockDim.x + threadIdx.x; e < E; e += stride) {
        int src = edge_at(edges, e, is64);
        int dst = edge_at(edges, E + e, is64);
        csr[offs[dst] + rank[e]] = src;
    }
}

// ---------------------------------------------------------------------------
// Aggregate: one wave per node, single pass, padded straight-line 8-wide
// gathers, next-batch csr/a_src prefetch.
// ---------------------------------------------------------------------------
__global__ __launch_bounds__(256) void agg_kernel(const __half* __restrict__ xh,
                                                  const float* __restrict__ a_src,
                                                  const float* __restrict__ a_dst,
                                                  const int* __restrict__ offs,
                                                  const int* __restrict__ csr,
                                                  const float* __restrict__ bias,
                                                  float* __restrict__ out, int N) {
    int node = blockIdx.x * 4 + (threadIdx.x >> 6);
    if (node >= N) return;
    int l = threadIdx.x & 63;
    int h8 = l & 7;
    int e8 = l >> 3;
    int hg = l >> 3;

    float ad_w = a_dst[node * 8 + h8];
    float wself = expf(leaky_relu_f(a_src[node * 8 + h8] + ad_w));
    float spart = (e8 == 0) ? wself : 0.f;

    float wself_h = __shfl(wself, hg);
    float2 xs = __half22float2(*(const __half2*)&xh[(long long)node * 128 + 2 * l]);
    float accx = wself_h * xs.x;
    float accy = wself_h * xs.y;

    int beg = offs[node], end = offs[node + 1];
    int srcv = 0;
    float w = 0.f;
    if (beg < end) {
        srcv = csr[beg + e8];
        w = expf(leaky_relu_f(a_src[srcv * 8 + h8] + ad_w));
    }
    for (int p = beg; p < end; p += 8) {
        spart += w;
        int pn = p + 8;
        int srcv_n = 0;
        float asv_n = 0.f;
        bool more = pn < end;
        if (more) {
            srcv_n = csr[pn + e8];
            asv_n = a_src[srcv_n * 8 + h8];
        }
        float wcur = w;
        int srcv_c = srcv;
#pragma unroll
        for (int e = 0; e < 8; e++) {
            int src = __shfl(srcv_c, e * 8);
            float we = __shfl(wcur, e * 8 + hg);
            float2 xv = __half22float2(*(const __half2*)&xh[(long long)src * 128 + 2 * l]);
            accx = fmaf(we, xv.x, accx);
            accy = fmaf(we, xv.y, accy);
        }
        w = more ? expf(leaky_relu_f(asv_n + ad_w)) : 0.f;
        srcv = srcv_n;
    }
    spart += __shfl_xor(spart, 8);
    spart += __shfl_xor(spart, 16);
    spart += __shfl_xor(spart, 32);
    float s = __shfl(spart, hg);
    float inv = 1.f / (s + 1e-16f);

    float2 b = *(const float2*)&bias[2 * l];
    float2 o;
    o.x = selu_f(fmaf(accx, inv, b.x));
    o.y = selu_f(fmaf(accy, inv, b.y));
    *(float2*)&out[(long long)node * 128 + 2 * l] = o;
}

extern "C" void kernel_launch(void* const* d_in, const int* in_sizes, int n_in,
                              void* d_out, int out_size, void* d_ws, size_t ws_size,
                              hipStream_t stream) {
    const float* feats   = (const float*)d_in[0];
    const void*  edges   = d_in[1];
    const float* W       = (const float*)d_in[2];
    const float* att_src = (const float*)d_in[3];
    const float* att_dst = (const float*)d_in[4];
    const float* bias    = (const float*)d_in[5];

    const int N = in_sizes[0] / 128;
    const long long E = in_sizes[1] / 2;
    const long long fillE = E + 7LL * N;
    float* out = (float*)d_out;

    char* ws = (char*)d_ws;
    __half* xh    = (__half*)ws; ws += (size_t)(N + 1) * 128 * 2;
    float* a_src  = (float*)ws;  ws += (size_t)(N + 1) * 8 * 4;
    float* a_dst  = (float*)ws;  ws += (size_t)N * 8 * 4;
    int*   deg    = (int*)ws;    ws += (size_t)N * 4;
    int*   offs   = (int*)ws;    ws += (size_t)(N + 1) * 4;
    int*   rank   = (int*)ws;    ws += (size_t)E * 4;
    int*   bsum   = (int*)ws;    ws += 1028 * 4;
    int*   csr    = (int*)ws;    ws += (size_t)fillE * 4;

    int nb = (N + 1023) / 1024;
    zero_kernel<<<(N + 255) / 256, 256, 0, stream>>>(deg, N);
    hist_kernel<<<2048, 256, 0, stream>>>(edges, E, deg, rank);
    scan1_kernel<<<nb, 256, 0, stream>>>(deg, offs, bsum, N);
    scan2_kernel<<<1, 1024, 0, stream>>>(bsum, nb);
    scan3_kernel<<<(N + 256) / 256, 256, 0, stream>>>(offs, bsum, deg, csr, N, nb);
    gemm_kernel<<<(N + 31) / 32, 256, 0, stream>>>(feats, W, att_src, att_dst, xh, a_src, a_dst, N);
    scatter_kernel<<<2048, 256, 0, stream>>>(edges, E, offs, rank, csr);
    agg_kernel<<<(N + 3) / 4, 256, 0, stream>>>(xh, a_src, a_dst, offs, csr, bias, out, N);
}